// Round 3
// baseline (204.849 us; speedup 1.0000x reference)
//
#include <hip/hip_runtime.h>
#include <math.h>

// Problem constants (from reference setup_inputs)
#define N_SAMPLES 131072
#define DIM 256
#define C_CLASSES 100
#define K_BALLS 2
#define M_BALLS 200          // C*K
#define MARGIN_M 0.5f

// Grid layout: blocks [0, NB_INTRA) do the intra term, blocks
// [NB_INTRA, NB_INTRA+NB_PAIR) do overlap+diversity pairs.
#define NB_INTRA 2048
#define JCHUNKS 13                     // ceil(208/16): 16 j's per pair-block
#define NB_PAIR (M_BALLS * JCHUNKS)    // 2600

// ws layout (doubles), all plain stores (no zeroing, no atomics):
//   [0, 2048)            intra partial per block
//   [2048, 2048+2600)    overlap partial per pair-block
//   [4648, 4648+2600)    diversity partial per pair-block
#define WS_OV_OFF 2048
#define WS_DV_OFF (2048 + NB_PAIR)

__device__ __forceinline__ void acc_sq(const float4 x, const float4 y, float& d) {
    float t;
    t = x.x - y.x; d = fmaf(t, t, d);
    t = x.y - y.y; d = fmaf(t, t, d);
    t = x.z - y.z; d = fmaf(t, t, d);
    t = x.w - y.w; d = fmaf(t, t, d);
}

// Fused main kernel.
// Intra: 4 samples per wave (16-lane group per sample, lane owns 16 floats),
//        4 iterations -> 16 samples/wave; 2048 blocks x 4 waves = 131072.
// Pair:  block pb = blockIdx.x - NB_INTRA; i = pb/13, j-chunk = pb%13;
//        each wave handles 4 j's in 16-lane groups.
__global__ __launch_bounds__(256) void main_kernel(
    const float* __restrict__ z,
    const int* __restrict__ labels,
    const float* __restrict__ centers,   // [C, K, D] == flat [M, D]
    const float* __restrict__ radii_raw, // [C, K] == flat [M]
    double* __restrict__ ws)
{
    __shared__ float sh[8];
    const int lane = threadIdx.x & 63;
    const int wv = threadIdx.x >> 6;
    const int grp = lane >> 4;   // 16-lane group id (0..3)
    const int sl = lane & 15;    // lane within group

    if (blockIdx.x < NB_INTRA) {
        // ---------------- intra term ----------------
        const int gwave = blockIdx.x * 4 + wv;
        const int base = gwave * 16;

        // lanes 0-15 hold the wave's 16 labels, one coalesced load
        const int lab = labels[base + sl];

        float acc = 0.0f;

        #pragma unroll
        for (int it = 0; it < 4; ++it) {
            const int n = base + it * 4 + grp;
            const int lbl = __shfl(lab, it * 4 + grp, 64);

            const float* zp = z + (size_t)n * DIM + sl * 4;
            const float* cp = centers + (size_t)lbl * (2 * DIM) + sl * 4;

            const float4 z0 = *(const float4*)(zp);
            const float4 z1 = *(const float4*)(zp + 64);
            const float4 z2 = *(const float4*)(zp + 128);
            const float4 z3 = *(const float4*)(zp + 192);
            const float4 a0 = *(const float4*)(cp);
            const float4 a1 = *(const float4*)(cp + 64);
            const float4 a2 = *(const float4*)(cp + 128);
            const float4 a3 = *(const float4*)(cp + 192);
            const float4 b0 = *(const float4*)(cp + 256);
            const float4 b1 = *(const float4*)(cp + 320);
            const float4 b2 = *(const float4*)(cp + 384);
            const float4 b3 = *(const float4*)(cp + 448);

            float d0 = 0.0f, d1 = 0.0f;
            acc_sq(z0, a0, d0); acc_sq(z1, a1, d0); acc_sq(z2, a2, d0); acc_sq(z3, a3, d0);
            acc_sq(z0, b0, d1); acc_sq(z1, b1, d1); acc_sq(z2, b2, d1); acc_sq(z3, b3, d1);

            #pragma unroll
            for (int m = 1; m <= 8; m <<= 1) {
                d0 += __shfl_xor(d0, m, 64);
                d1 += __shfl_xor(d1, m, 64);
            }

            if (sl == 0) {
                const float r0 = fabsf(radii_raw[lbl * 2 + 0]) + 1e-6f;
                const float r1 = fabsf(radii_raw[lbl * 2 + 1]) + 1e-6f;
                // stable softmax over K=2 of -d/tau  (1/TAU_B = 2)
                const float s0 = -d0 * 2.0f;
                const float s1 = -d1 * 2.0f;
                const float mx = fmaxf(s0, s1);
                const float e0 = expf(s0 - mx);
                const float e1 = expf(s1 - mx);
                const float inv = 1.0f / (e0 + e1);
                const float q0 = e0 * inv, q1 = e1 * inv;
                const float dsw = q0 * d0 + q1 * d1;
                const float rsw = q0 * r0 * r0 + q1 * r1 * r1;  // ETA = 1
                acc += fmaxf(dsw - rsw, 0.0f);
            }
        }

        acc += __shfl_xor(acc, 16, 64);
        acc += __shfl_xor(acc, 32, 64);
        if (lane == 0) sh[wv] = acc;
        __syncthreads();
        if (threadIdx.x == 0)
            ws[blockIdx.x] = (double)(sh[0] + sh[1] + sh[2] + sh[3]);
    } else {
        // ---------------- overlap + diversity pairs ----------------
        const int pb = blockIdx.x - NB_INTRA;
        const int i = pb / JCHUNKS;
        const int jchunk = pb - i * JCHUNKS;
        const int j = jchunk * 16 + wv * 4 + grp;
        const int jc = j < M_BALLS ? j : M_BALLS - 1;  // clamp addr, mask result

        const float* ip = centers + (size_t)i * DIM + sl * 4;
        const float* jp = centers + (size_t)jc * DIM + sl * 4;

        const float4 i0 = *(const float4*)(ip);
        const float4 i1 = *(const float4*)(ip + 64);
        const float4 i2 = *(const float4*)(ip + 128);
        const float4 i3 = *(const float4*)(ip + 192);
        const float4 j0 = *(const float4*)(jp);
        const float4 j1 = *(const float4*)(jp + 64);
        const float4 j2 = *(const float4*)(jp + 128);
        const float4 j3 = *(const float4*)(jp + 192);

        float s = 0.0f;
        acc_sq(i0, j0, s); acc_sq(i1, j1, s); acc_sq(i2, j2, s); acc_sq(i3, j3, s);

        #pragma unroll
        for (int m = 1; m <= 8; m <<= 1)
            s += __shfl_xor(s, m, 64);

        float ov = 0.0f, dv = 0.0f;
        if (sl == 0 && j < M_BALLS && j != i) {
            const float d = sqrtf(s);
            const float ri = fabsf(radii_raw[i]) + 1e-6f;
            const float rj = fabsf(radii_raw[j]) + 1e-6f;
            ov = fmaxf(ri + rj + MARGIN_M - d, 0.0f);
            // diversity: within-class pair p<q == (even i, j==i+1)
            if (((i & 1) == 0) && (j == i + 1))
                dv = fmaxf(1.0f - d, 0.0f);
        }
        ov += __shfl_xor(ov, 16, 64);
        ov += __shfl_xor(ov, 32, 64);
        dv += __shfl_xor(dv, 16, 64);
        dv += __shfl_xor(dv, 32, 64);

        if (lane == 0) { sh[wv] = ov; sh[4 + wv] = dv; }
        __syncthreads();
        if (threadIdx.x == 0) {
            ws[WS_OV_OFF + pb] = (double)(sh[0] + sh[1] + sh[2] + sh[3]);
            ws[WS_DV_OFF + pb] = (double)(sh[4] + sh[5] + sh[6] + sh[7]);
        }
    }
}

// One block, 256 threads: reduce all partials and write the 4 outputs.
__global__ __launch_bounds__(256) void finalize_kernel(
    const double* __restrict__ ws, float* __restrict__ out)
{
    __shared__ double shi[4], sho[4], shd[4];
    const int t = threadIdx.x;
    const int lane = t & 63;
    const int wv = t >> 6;

    double si = 0.0, so = 0.0, sd = 0.0;
    for (int k = t; k < NB_INTRA; k += 256) si += ws[k];
    for (int k = t; k < NB_PAIR; k += 256) {
        so += ws[WS_OV_OFF + k];
        sd += ws[WS_DV_OFF + k];
    }
    #pragma unroll
    for (int m = 1; m <= 32; m <<= 1) {
        si += __shfl_xor(si, m, 64);
        so += __shfl_xor(so, m, 64);
        sd += __shfl_xor(sd, m, 64);
    }
    if (lane == 0) { shi[wv] = si; sho[wv] = so; shd[wv] = sd; }
    __syncthreads();
    if (t == 0) {
        const double ti = shi[0] + shi[1] + shi[2] + shi[3];
        const double to = sho[0] + sho[1] + sho[2] + sho[3];
        const double td = shd[0] + shd[1] + shd[2] + shd[3];
        const double L_intra = ti / (double)N_SAMPLES;
        const double L_overlap = to / (double)(M_BALLS * (M_BALLS - 1));       // 39800
        const double L_div = td / (double)(C_CLASSES * K_BALLS * (K_BALLS - 1) / 2); // 100
        const double total = L_intra + L_overlap + 0.5 * L_div;
        out[0] = (float)total;
        out[1] = (float)L_intra;
        out[2] = (float)L_overlap;
        out[3] = (float)L_div;
    }
}

extern "C" void kernel_launch(void* const* d_in, const int* in_sizes, int n_in,
                              void* d_out, int out_size, void* d_ws, size_t ws_size,
                              hipStream_t stream) {
    const float* z = (const float*)d_in[0];
    const int* labels = (const int*)d_in[1];
    const float* centers = (const float*)d_in[2];
    const float* radii = (const float*)d_in[3];
    float* out = (float*)d_out;
    double* ws = (double*)d_ws;

    main_kernel<<<NB_INTRA + NB_PAIR, 256, 0, stream>>>(z, labels, centers, radii, ws);
    finalize_kernel<<<1, 256, 0, stream>>>(ws, out);
}

// Round 5
// 202.016 us; speedup vs baseline: 1.0140x; 1.0140x over previous
//
#include <hip/hip_runtime.h>
#include <math.h>

// Problem constants (from reference setup_inputs)
#define N_SAMPLES 131072
#define DIM 256
#define C_CLASSES 100
#define K_BALLS 2
#define M_BALLS 200          // C*K
#define MARGIN_M 0.5f

// Grid layout: blocks [0, NB_INTRA) do the intra term, blocks
// [NB_INTRA, NB_INTRA+NB_PAIR) do overlap+diversity pairs.
#define NB_INTRA 2048
#define JCHUNKS 13                     // ceil(208/16): 16 j's per pair-block
#define NB_PAIR (M_BALLS * JCHUNKS)    // 2600

// ws layout (doubles), all plain stores (no zeroing, no atomics):
//   [0, 2048)            intra partial per block
//   [2048, 2048+2600)    overlap partial per pair-block
//   [4648, 4648+2600)    diversity partial per pair-block
#define WS_OV_OFF 2048
#define WS_DV_OFF (2048 + NB_PAIR)

// native vector type (works with __builtin_nontemporal_load, unlike
// HIP_vector_type<float,4>)
typedef float vf4 __attribute__((ext_vector_type(4)));

__device__ __forceinline__ void acc_sq(const vf4 x, const vf4 y, float& d) {
    float t;
    t = x.x - y.x; d = fmaf(t, t, d);
    t = x.y - y.y; d = fmaf(t, t, d);
    t = x.z - y.z; d = fmaf(t, t, d);
    t = x.w - y.w; d = fmaf(t, t, d);
}

// Fused main kernel.
// Intra: 4 samples per wave (16-lane group per sample, lane owns 16 floats),
//        4 iterations -> 16 samples/wave; 2048 blocks x 4 waves = 131072.
//        z is streamed with non-temporal loads (read-once data); centers/radii
//        stay on the normal cached path (hot in L1/L2).
// Pair:  block pb = blockIdx.x - NB_INTRA; i = pb/13, j-chunk = pb%13;
//        each wave handles 4 j's in 16-lane groups.
// __launch_bounds__(256,4): cap VGPRs at 128 so >=4 waves/SIMD stay resident
// (loads in flight are what hide the z-stream latency).
__global__ __launch_bounds__(256, 4) void main_kernel(
    const float* __restrict__ z,
    const int* __restrict__ labels,
    const float* __restrict__ centers,   // [C, K, D] == flat [M, D]
    const float* __restrict__ radii_raw, // [C, K] == flat [M]
    double* __restrict__ ws)
{
    __shared__ float sh[8];
    const int lane = threadIdx.x & 63;
    const int wv = threadIdx.x >> 6;
    const int grp = lane >> 4;   // 16-lane group id (0..3)
    const int sl = lane & 15;    // lane within group

    if (blockIdx.x < NB_INTRA) {
        // ---------------- intra term ----------------
        const int gwave = blockIdx.x * 4 + wv;
        const int base = gwave * 16;

        // lanes 0-15 hold the wave's 16 labels, one coalesced load
        const int lab = labels[base + sl];

        float acc = 0.0f;

        #pragma unroll
        for (int it = 0; it < 4; ++it) {
            const int n = base + it * 4 + grp;
            const int lbl = __shfl(lab, it * 4 + grp, 64);

            const float* zp = z + (size_t)n * DIM + sl * 4;
            const float* cp = centers + (size_t)lbl * (2 * DIM) + sl * 4;

            // z: non-temporal streaming loads (read-once)
            const vf4 z0 = __builtin_nontemporal_load((const vf4*)(zp));
            const vf4 z1 = __builtin_nontemporal_load((const vf4*)(zp + 64));
            const vf4 z2 = __builtin_nontemporal_load((const vf4*)(zp + 128));
            const vf4 z3 = __builtin_nontemporal_load((const vf4*)(zp + 192));
            // centers: cached path
            const vf4 a0 = *(const vf4*)(cp);
            const vf4 a1 = *(const vf4*)(cp + 64);
            const vf4 a2 = *(const vf4*)(cp + 128);
            const vf4 a3 = *(const vf4*)(cp + 192);
            const vf4 b0 = *(const vf4*)(cp + 256);
            const vf4 b1 = *(const vf4*)(cp + 320);
            const vf4 b2 = *(const vf4*)(cp + 384);
            const vf4 b3 = *(const vf4*)(cp + 448);

            float d0 = 0.0f, d1 = 0.0f;
            acc_sq(z0, a0, d0); acc_sq(z1, a1, d0); acc_sq(z2, a2, d0); acc_sq(z3, a3, d0);
            acc_sq(z0, b0, d1); acc_sq(z1, b1, d1); acc_sq(z2, b2, d1); acc_sq(z3, b3, d1);

            #pragma unroll
            for (int m = 1; m <= 8; m <<= 1) {
                d0 += __shfl_xor(d0, m, 64);
                d1 += __shfl_xor(d1, m, 64);
            }

            if (sl == 0) {
                const float r0 = fabsf(radii_raw[lbl * 2 + 0]) + 1e-6f;
                const float r1 = fabsf(radii_raw[lbl * 2 + 1]) + 1e-6f;
                // stable softmax over K=2 of -d/tau  (1/TAU_B = 2)
                const float s0 = -d0 * 2.0f;
                const float s1 = -d1 * 2.0f;
                const float mx = fmaxf(s0, s1);
                const float e0 = expf(s0 - mx);
                const float e1 = expf(s1 - mx);
                const float inv = 1.0f / (e0 + e1);
                const float q0 = e0 * inv, q1 = e1 * inv;
                const float dsw = q0 * d0 + q1 * d1;
                const float rsw = q0 * r0 * r0 + q1 * r1 * r1;  // ETA = 1
                acc += fmaxf(dsw - rsw, 0.0f);
            }
        }

        acc += __shfl_xor(acc, 16, 64);
        acc += __shfl_xor(acc, 32, 64);
        if (lane == 0) sh[wv] = acc;
        __syncthreads();
        if (threadIdx.x == 0)
            ws[blockIdx.x] = (double)(sh[0] + sh[1] + sh[2] + sh[3]);
    } else {
        // ---------------- overlap + diversity pairs ----------------
        const int pb = blockIdx.x - NB_INTRA;
        const int i = pb / JCHUNKS;
        const int jchunk = pb - i * JCHUNKS;
        const int j = jchunk * 16 + wv * 4 + grp;
        const int jc = j < M_BALLS ? j : M_BALLS - 1;  // clamp addr, mask result

        const float* ip = centers + (size_t)i * DIM + sl * 4;
        const float* jp = centers + (size_t)jc * DIM + sl * 4;

        const vf4 i0 = *(const vf4*)(ip);
        const vf4 i1 = *(const vf4*)(ip + 64);
        const vf4 i2 = *(const vf4*)(ip + 128);
        const vf4 i3 = *(const vf4*)(ip + 192);
        const vf4 j0 = *(const vf4*)(jp);
        const vf4 j1 = *(const vf4*)(jp + 64);
        const vf4 j2 = *(const vf4*)(jp + 128);
        const vf4 j3 = *(const vf4*)(jp + 192);

        float s = 0.0f;
        acc_sq(i0, j0, s); acc_sq(i1, j1, s); acc_sq(i2, j2, s); acc_sq(i3, j3, s);

        #pragma unroll
        for (int m = 1; m <= 8; m <<= 1)
            s += __shfl_xor(s, m, 64);

        float ov = 0.0f, dv = 0.0f;
        if (sl == 0 && j < M_BALLS && j != i) {
            const float d = sqrtf(s);
            const float ri = fabsf(radii_raw[i]) + 1e-6f;
            const float rj = fabsf(radii_raw[j]) + 1e-6f;
            ov = fmaxf(ri + rj + MARGIN_M - d, 0.0f);
            // diversity: within-class pair p<q == (even i, j==i+1)
            if (((i & 1) == 0) && (j == i + 1))
                dv = fmaxf(1.0f - d, 0.0f);
        }
        ov += __shfl_xor(ov, 16, 64);
        ov += __shfl_xor(ov, 32, 64);
        dv += __shfl_xor(dv, 16, 64);
        dv += __shfl_xor(dv, 32, 64);

        if (lane == 0) { sh[wv] = ov; sh[4 + wv] = dv; }
        __syncthreads();
        if (threadIdx.x == 0) {
            ws[WS_OV_OFF + pb] = (double)(sh[0] + sh[1] + sh[2] + sh[3]);
            ws[WS_DV_OFF + pb] = (double)(sh[4] + sh[5] + sh[6] + sh[7]);
        }
    }
}

// One block, 256 threads: reduce all partials and write the 4 outputs.
__global__ __launch_bounds__(256) void finalize_kernel(
    const double* __restrict__ ws, float* __restrict__ out)
{
    __shared__ double shi[4], sho[4], shd[4];
    const int t = threadIdx.x;
    const int lane = t & 63;
    const int wv = t >> 6;

    double si = 0.0, so = 0.0, sd = 0.0;
    for (int k = t; k < NB_INTRA; k += 256) si += ws[k];
    for (int k = t; k < NB_PAIR; k += 256) {
        so += ws[WS_OV_OFF + k];
        sd += ws[WS_DV_OFF + k];
    }
    #pragma unroll
    for (int m = 1; m <= 32; m <<= 1) {
        si += __shfl_xor(si, m, 64);
        so += __shfl_xor(so, m, 64);
        sd += __shfl_xor(sd, m, 64);
    }
    if (lane == 0) { shi[wv] = si; sho[wv] = so; shd[wv] = sd; }
    __syncthreads();
    if (t == 0) {
        const double ti = shi[0] + shi[1] + shi[2] + shi[3];
        const double to = sho[0] + sho[1] + sho[2] + sho[3];
        const double td = shd[0] + shd[1] + shd[2] + shd[3];
        const double L_intra = ti / (double)N_SAMPLES;
        const double L_overlap = to / (double)(M_BALLS * (M_BALLS - 1));       // 39800
        const double L_div = td / (double)(C_CLASSES * K_BALLS * (K_BALLS - 1) / 2); // 100
        const double total = L_intra + L_overlap + 0.5 * L_div;
        out[0] = (float)total;
        out[1] = (float)L_intra;
        out[2] = (float)L_overlap;
        out[3] = (float)L_div;
    }
}

extern "C" void kernel_launch(void* const* d_in, const int* in_sizes, int n_in,
                              void* d_out, int out_size, void* d_ws, size_t ws_size,
                              hipStream_t stream) {
    const float* z = (const float*)d_in[0];
    const int* labels = (const int*)d_in[1];
    const float* centers = (const float*)d_in[2];
    const float* radii = (const float*)d_in[3];
    float* out = (float*)d_out;
    double* ws = (double*)d_ws;

    main_kernel<<<NB_INTRA + NB_PAIR, 256, 0, stream>>>(z, labels, centers, radii, ws);
    finalize_kernel<<<1, 256, 0, stream>>>(ws, out);
}